// Round 6
// baseline (345.988 us; speedup 1.0000x reference)
//
#include <hip/hip_runtime.h>
#include <stdint.h>

#define B_    8
#define T_    769
#define C_    1024
#define H_    16
#define COND_ 256
#define NTOK  (B_*T_)     // 6152
#define BH_   (B_*H_)     // 128
#define TP_   896         // padded T for V^T rows

typedef short    v8s  __attribute__((ext_vector_type(8)));   // 8 bf16 (4 VGPRs)
typedef float    v4f  __attribute__((ext_vector_type(4)));   // 4 fp32 acc
typedef uint16_t u16x4 __attribute__((ext_vector_type(4)));
typedef uint16_t u16x8 __attribute__((ext_vector_type(8)));

__device__ __forceinline__ uint16_t f2bf(float f) {
  uint32_t u = __builtin_bit_cast(uint32_t, f);
  u += 0x7fffu + ((u >> 16) & 1u);          // RNE
  return (uint16_t)(u >> 16);
}
__device__ __forceinline__ float bf2f(uint16_t h) {
  uint32_t u = ((uint32_t)h) << 16;
  return __builtin_bit_cast(float, u);
}

__device__ __forceinline__ void gl_lds16(const void* gptr, void* lptr) {
  __builtin_amdgcn_global_load_lds(
      (const __attribute__((address_space(1))) uint32_t*)gptr,
      (__attribute__((address_space(3))) uint32_t*)lptr,
      16, 0, 0);
}

// ---------------------------------------------------------------- convert f32->bf16
__global__ __launch_bounds__(256) void convert_bf16(
    const float* xq, const float* xkv, const float* wq, const float* wk,
    const float* wv, const float* wp,
    uint16_t* dxq, uint16_t* dxkv, uint16_t* dwq, uint16_t* dwk,
    uint16_t* dwv, uint16_t* dwp)
{
  int bid = blockIdx.x;
  const float* s; uint16_t* d; int base;
  if (bid < 6152)       { s = xq;  d = dxq;  base = bid; }
  else if (bid < 12304) { s = xkv; d = dxkv; base = bid - 6152; }
  else {
    int r = bid - 12304;
    int wsel = r >> 10; base = r & 1023;
    s = (wsel == 0) ? wq : (wsel == 1) ? wk : (wsel == 2) ? wv : wp;
    d = (wsel == 0) ? dwq : (wsel == 1) ? dwk : (wsel == 2) ? dwv : dwp;
  }
  int i = base * 256 + threadIdx.x;
  float4 f = ((const float4*)s)[i];
  u16x4 o;
  o[0] = f2bf(f.x); o[1] = f2bf(f.y); o[2] = f2bf(f.z); o[3] = f2bf(f.w);
  ((u16x4*)d)[i] = o;
}

// ---------------------------------------------------------------- GEMM mainloop
// A-direct: A frags global->VGPR (16B/lane, L2-served, no barrier dependency).
// B-only LDS staging, BK=128 (32 KB), 16-chunk XOR swizzle, 8 K-iters.
__device__ __forceinline__ void gemm_mainloop_ad(
    const uint16_t* A, const uint16_t* W, int M, int row0, int col0,
    v4f acc[4][4], uint16_t* sB)
{
  const int tid = threadIdx.x;
  const int lane = tid & 63, w = tid >> 6, quad = lane >> 4, l15 = lane & 15;
  const int rbase = (w >> 1) * 64, cbase = (w & 1) * 64;

  const uint16_t* Arow[4];
  #pragma unroll
  for (int i = 0; i < 4; i++)
    Arow[i] = A + (size_t)min(row0 + rbase + i * 16 + l15, M - 1) * 1024 + quad * 8;

  const uint16_t* Bptr[8];
  #pragma unroll
  for (int r = 0; r < 8; r++) {
    int c = r * 256 + tid;
    int row = c >> 4, p = c & 15;
    int g = (p & 8) | ((p ^ row) & 7);
    Bptr[r] = W + (size_t)(col0 + row) * 1024 + g * 8;
  }

  #pragma unroll
  for (int i = 0; i < 4; i++)
    #pragma unroll
    for (int j = 0; j < 4; j++) acc[i][j] = (v4f)0.0f;

  for (int k0 = 0; k0 < 1024; k0 += 128) {
    #pragma unroll
    for (int r = 0; r < 8; r++)
      gl_lds16(Bptr[r] + k0, sB + (r * 256 + tid) * 8);
    __syncthreads();
    #pragma unroll
    for (int ks = 0; ks < 4; ks++) {
      v8s af[4], bf[4];
      #pragma unroll
      for (int i = 0; i < 4; i++)
        af[i] = *(const v8s*)(Arow[i] + k0 + ks * 32);
      const int q = ks * 4 + quad;
      #pragma unroll
      for (int j = 0; j < 4; j++) {
        int n = cbase + j * 16 + l15;
        int p = (q & 8) | ((q ^ n) & 7);
        bf[j] = *(const v8s*)(sB + n * 128 + p * 8);
      }
      #pragma unroll
      for (int i = 0; i < 4; i++)
        #pragma unroll
        for (int j = 0; j < 4; j++)
          acc[i][j] = __builtin_amdgcn_mfma_f32_16x16x32_bf16(af[i], bf[j], acc[i][j], 0, 0, 0);
    }
    __syncthreads();
  }
}

// Fused QKV projection (Wqkv packed [3072][1024]; ct>>3 selects Q/K/V).
__global__ __launch_bounds__(256) void gemm_qkv(
    const uint16_t* xq, const uint16_t* xkv, const uint16_t* Wqkv,
    const float* bq, const float* bk, const float* bv, const float* freqs,
    uint16_t* Q, uint16_t* K, uint16_t* V)
{
  __shared__ uint16_t sB[128 * 128];
  const int ct = blockIdx.x, rt = blockIdx.y;
  const int z = ct >> 3;
  const int col0 = ct * 128, row0 = rt * 128;
  const uint16_t* A = (z == 0) ? xq : xkv;
  const float* bias  = (z == 0) ? bq : (z == 1 ? bk : bv);
  uint16_t* dst      = (z == 0) ? Q  : (z == 1 ? K  : V);

  v4f acc[4][4];
  gemm_mainloop_ad(A, Wqkv, NTOK, row0, col0, acc, sB);

  const int tid = threadIdx.x;
  const int lane = tid & 63, w = tid >> 6, quad = lane >> 4, l15 = lane & 15;
  const int rbase = (w >> 1) * 64, cbase = (w & 1) * 64;
  #pragma unroll
  for (int i = 0; i < 4; i++) {
    #pragma unroll
    for (int reg = 0; reg < 4; reg++) {
      int n = row0 + rbase + i * 16 + quad * 4 + reg;
      bool ok = (n < NTOK);
      int nn = min(n, NTOK - 1);
      int b = nn / T_, t = nn % T_;
      float vj[4];
      #pragma unroll
      for (int j = 0; j < 4; j++)
        vj[j] = acc[i][j][reg] + bias[(col0 + cbase + j * 16 + l15) & 1023];
      if (z < 2) {
        float v0 = vj[0], v1 = vj[1];
        float p0 = __shfl_xor(v0, 1);
        float p1 = __shfl_xor(v1, 1);
        float f0 = freqs[t * 32 + l15];
        float f1 = freqs[t * 32 + 16 + l15];
        float s0, c0, s1, c1;
        __sincosf(f0, &s0, &c0);
        __sincosf(f1, &s1, &c1);
        if (l15 & 1) { vj[0] = v0 * c0 + p0 * s0; vj[1] = v1 * c1 + p1 * s1; }
        else         { vj[0] = v0 * c0 - p0 * s0; vj[1] = v1 * c1 - p1 * s1; }
      }
      if (z == 0) {
        #pragma unroll
        for (int j = 0; j < 4; j++) vj[j] *= 0.125f;
      }
      if (ok) {
        #pragma unroll
        for (int j = 0; j < 4; j++) {
          int col = col0 + cbase + j * 16 + l15;
          int h = (col >> 6) & 15, d = col & 63;
          dst[((size_t)(b * H_ + h) * T_ + t) * 64 + d] = f2bf(vj[j]);
        }
      }
    }
  }
}

// Output projection: f32 -> d_out [NTOK][1024]
__global__ __launch_bounds__(256) void gemm_out(
    const uint16_t* Y, const uint16_t* wp, const float* bp, float* out)
{
  __shared__ uint16_t sB[128 * 128];
  const int col0 = blockIdx.x * 128, row0 = blockIdx.y * 128;
  v4f acc[4][4];
  gemm_mainloop_ad(Y, wp, NTOK, row0, col0, acc, sB);

  const int tid = threadIdx.x;
  const int lane = tid & 63, w = tid >> 6, quad = lane >> 4, l15 = lane & 15;
  const int rbase = (w >> 1) * 64, cbase = (w & 1) * 64;
  #pragma unroll
  for (int i = 0; i < 4; i++) {
    #pragma unroll
    for (int reg = 0; reg < 4; reg++) {
      int n = row0 + rbase + i * 16 + quad * 4 + reg;
      if (n < NTOK) {
        #pragma unroll
        for (int j = 0; j < 4; j++) {
          int col = col0 + cbase + j * 16 + l15;
          out[(size_t)n * 1024 + col] = acc[i][j][reg] + bp[col];
        }
      }
    }
  }
}

// ---------------------------------------------------------------- V transpose
// Vb [bh][T][64] -> Vt [bh][64][TP_]. 64x64 tiles, XOR-swizzled LDS.
__global__ __launch_bounds__(256) void transpose_v(const uint16_t* Vb, uint16_t* Vt)
{
  __shared__ uint16_t sT[64 * 64];
  const int tid = threadIdx.x;
  const int t0 = blockIdx.x * 64, bh = blockIdx.y;
  const uint16_t* src = Vb + (size_t)bh * T_ * 64;
  #pragma unroll
  for (int r = 0; r < 2; r++) {
    int task = r * 256 + tid;
    int t = task >> 3, oc = task & 7;
    int gt = min(t0 + t, T_ - 1);
    u16x8 v = *(const u16x8*)(src + (size_t)gt * 64 + oc * 8);
    int p = oc ^ (t & 7) ^ ((t >> 3) & 7);
    *(u16x8*)(sT + t * 64 + p * 8) = v;
  }
  __syncthreads();
  uint16_t* dst = Vt + (size_t)bh * 64 * TP_;
  #pragma unroll
  for (int r = 0; r < 2; r++) {
    int task = r * 256 + tid;
    int o = task & 7, d = task >> 3;
    u16x8 v;
    #pragma unroll
    for (int k = 0; k < 8; k++) {
      int t = o * 8 + k;
      int p = (d >> 3) ^ k ^ o;
      v[k] = sT[t * 64 + p * 8 + (d & 7)];
    }
    *(u16x8*)(dst + (size_t)d * TP_ + t0 + o * 8) = v;
  }
}

// ---------------------------------------------------------------- flash attention
__global__ __launch_bounds__(256) void attn(
    const uint16_t* Q, const uint16_t* K, const uint16_t* Vt, uint16_t* Y)
{
  __shared__ uint16_t sK[128 * 64];
  __shared__ uint16_t sVT[64 * 128];
  __shared__ uint16_t sP[4 * 16 * 136];

  const int tid = threadIdx.x;
  const int lane = tid & 63, w = tid >> 6, quad = lane >> 4, l15 = lane & 15;
  const int bh = blockIdx.y, b = bh >> 4, h = bh & 15;
  const int q0 = blockIdx.x * 64;

  const uint16_t* Qb = Q + (size_t)bh * T_ * 64;
  const uint16_t* Kb = K + (size_t)bh * T_ * 64;
  const uint16_t* Vtb = Vt + (size_t)bh * 64 * TP_;

  const int qr = min(q0 + w * 16 + l15, T_ - 1);
  v8s aq0 = *(const v8s*)(Qb + (size_t)qr * 64 + quad * 8);
  v8s aq1 = *(const v8s*)(Qb + (size_t)qr * 64 + 32 + quad * 8);

  float l_r[4] = {0.f, 0.f, 0.f, 0.f};
  v4f o[4];
  #pragma unroll
  for (int r = 0; r < 4; r++) o[r] = (v4f)0.0f;

  const int kend = min(T_, q0 + 319);
  const int nkt = (kend + 127) >> 7;

  for (int kt = 0; kt < nkt; kt++) {
    const int k0 = kt * 128;
    #pragma unroll
    for (int r = 0; r < 4; r++) {
      int c = r * 256 + tid;
      int key = c >> 3, qp = c & 7;
      int g = qp ^ (key & 7);
      int gk = min(k0 + key, T_ - 1);
      gl_lds16(Kb + (size_t)gk * 64 + g * 8, sK + c * 8);
    }
    #pragma unroll
    for (int r = 0; r < 4; r++) {
      int c = r * 256 + tid;
      int d = c >> 4, p = c & 15;
      int g = (p & 8) | ((p ^ d) & 7);
      gl_lds16(Vtb + (size_t)d * TP_ + k0 + g * 8, sVT + c * 8);
    }
    __syncthreads();

    v4f s[8];
    #pragma unroll
    for (int cb = 0; cb < 8; cb++) {
      int key_l = cb * 16 + l15;
      v8s b0 = *(const v8s*)(sK + (key_l * 8 + ((quad) ^ (key_l & 7))) * 8);
      v8s b1 = *(const v8s*)(sK + (key_l * 8 + ((4 + quad) ^ (key_l & 7))) * 8);
      v4f zz = (v4f)0.0f;
      zz = __builtin_amdgcn_mfma_f32_16x16x32_bf16(aq0, b0, zz, 0, 0, 0);
      zz = __builtin_amdgcn_mfma_f32_16x16x32_bf16(aq1, b1, zz, 0, 0, 0);
      s[cb] = zz;
    }

    uint16_t* pw = sP + w * (16 * 136);
    const int qrow_base = q0 + w * 16 + quad * 4;
    const bool full = (k0 + 128 <= COND_ + q0) && (k0 + 128 <= T_);
    if (full) {
      #pragma unroll
      for (int reg = 0; reg < 4; reg++) {
        float rs = 0.f;
        #pragma unroll
        for (int cb = 0; cb < 8; cb++) {
          float pv = __expf(s[cb][reg]);
          uint16_t pb = f2bf(pv);
          rs += bf2f(pb);
          pw[(quad * 4 + reg) * 136 + cb * 16 + l15] = pb;
        }
        #pragma unroll
        for (int off = 1; off < 16; off <<= 1) rs += __shfl_xor(rs, off);
        l_r[reg] += rs;
      }
    } else {
      #pragma unroll
      for (int reg = 0; reg < 4; reg++) {
        int lim = min(COND_ + qrow_base + reg, T_);
        float rs = 0.f;
        #pragma unroll
        for (int cb = 0; cb < 8; cb++) {
          int key = k0 + cb * 16 + l15;
          float pv = (key < lim) ? __expf(s[cb][reg]) : 0.f;
          uint16_t pb = f2bf(pv);
          rs += bf2f(pb);
          pw[(quad * 4 + reg) * 136 + cb * 16 + l15] = pb;
        }
        #pragma unroll
        for (int off = 1; off < 16; off <<= 1) rs += __shfl_xor(rs, off);
        l_r[reg] += rs;
      }
    }

    #pragma unroll
    for (int ks = 0; ks < 4; ks++) {
      v8s ap = *(const v8s*)(pw + l15 * 136 + ks * 32 + quad * 8);
      #pragma unroll
      for (int cbd = 0; cbd < 4; cbd++) {
        int d = cbd * 16 + l15;
        v8s bv = *(const v8s*)(sVT + d * 128 + (((ks * 4 + quad) ^ (d & 7)) * 8));
        o[cbd] = __builtin_amdgcn_mfma_f32_16x16x32_bf16(ap, bv, o[cbd], 0, 0, 0);
      }
    }
    __syncthreads();
  }

  #pragma unroll
  for (int reg = 0; reg < 4; reg++) {
    int t = q0 + w * 16 + quad * 4 + reg;
    if (t < T_) {
      float inv = 1.0f / l_r[reg];
      #pragma unroll
      for (int cbd = 0; cbd < 4; cbd++) {
        int d = cbd * 16 + l15;
        Y[((size_t)(b * T_ + t)) * C_ + h * 64 + d] = f2bf(o[cbd][reg] * inv);
      }
    }
  }
}

// ---------------------------------------------------------------- launch
extern "C" void kernel_launch(void* const* d_in, const int* in_sizes, int n_in,
                              void* d_out, int out_size, void* d_ws, size_t ws_size,
                              hipStream_t stream)
{
  const float* x_q   = (const float*)d_in[0];
  const float* x_kv  = (const float*)d_in[1];
  const float* freqs = (const float*)d_in[2];
  const float* Wq = (const float*)d_in[3];
  const float* bq = (const float*)d_in[4];
  const float* Wk = (const float*)d_in[5];
  const float* bk = (const float*)d_in[6];
  const float* Wv = (const float*)d_in[7];
  const float* bv = (const float*)d_in[8];
  const float* Wp = (const float*)d_in[9];
  const float* bp = (const float*)d_in[10];
  float* out = (float*)d_out;

  const size_t SZX = (size_t)NTOK * C_;
  const size_t SZW = (size_t)C_ * C_;
  uint16_t* ws = (uint16_t*)d_ws;
  uint16_t* xq_bf  = ws;
  uint16_t* xkv_bf = xq_bf + SZX;
  uint16_t* wq_bf  = xkv_bf + SZX;   // packed Wqkv[3072][1024]
  uint16_t* wk_bf  = wq_bf + SZW;
  uint16_t* wv_bf  = wk_bf + SZW;
  uint16_t* wp_bf  = wv_bf + SZW;
  uint16_t* Qb = wp_bf + SZW;
  uint16_t* Kb = Qb + SZX;
  uint16_t* Vb = Kb + SZX;
  uint16_t* Vt = ws;                 // alias over dead xq/xkv after qkv
  uint16_t* Yb = Vb;                 // alias over dead natural-V after transpose

  convert_bf16<<<dim3(16400), 256, 0, stream>>>(
      x_q, x_kv, Wq, Wk, Wv, Wp, xq_bf, xkv_bf, wq_bf, wk_bf, wv_bf, wp_bf);

  gemm_qkv<<<dim3(24, 49), 256, 0, stream>>>(
      xq_bf, xkv_bf, wq_bf, bq, bk, bv, freqs, Qb, Kb, Vb);

  transpose_v<<<dim3(13, BH_), 256, 0, stream>>>(Vb, Vt);

  attn<<<dim3(13, BH_), 256, 0, stream>>>(Qb, Kb, Vt, Yb);

  gemm_out<<<dim3(8, 49), 256, 0, stream>>>(Yb, wp_bf, bp, out);
}

// Round 7
// 291.939 us; speedup vs baseline: 1.1851x; 1.1851x over previous
//
#include <hip/hip_runtime.h>
#include <stdint.h>

#define B_    8
#define T_    769
#define C_    1024
#define H_    16
#define COND_ 256
#define NTOK  (B_*T_)     // 6152
#define BH_   (B_*H_)     // 128
#define TP_   896         // padded T for V^T rows

typedef short    v8s  __attribute__((ext_vector_type(8)));   // 8 bf16 (4 VGPRs)
typedef float    v4f  __attribute__((ext_vector_type(4)));   // 4 fp32 acc
typedef uint16_t u16x4 __attribute__((ext_vector_type(4)));
typedef uint16_t u16x8 __attribute__((ext_vector_type(8)));

__device__ __forceinline__ uint16_t f2bf(float f) {
  uint32_t u = __builtin_bit_cast(uint32_t, f);
  u += 0x7fffu + ((u >> 16) & 1u);          // RNE
  return (uint16_t)(u >> 16);
}
__device__ __forceinline__ float bf2f(uint16_t h) {
  uint32_t u = ((uint32_t)h) << 16;
  return __builtin_bit_cast(float, u);
}

__device__ __forceinline__ void gl_lds16(const void* gptr, void* lptr) {
  __builtin_amdgcn_global_load_lds(
      (const __attribute__((address_space(1))) uint32_t*)gptr,
      (__attribute__((address_space(3))) uint32_t*)lptr,
      16, 0, 0);
}

// ---------------------------------------------------------------- convert f32->bf16
__global__ __launch_bounds__(256) void convert_bf16(
    const float* xq, const float* xkv, const float* wq, const float* wk,
    const float* wv, const float* wp,
    uint16_t* dxq, uint16_t* dxkv, uint16_t* dwq, uint16_t* dwk,
    uint16_t* dwv, uint16_t* dwp)
{
  int bid = blockIdx.x;
  const float* s; uint16_t* d; int base;
  if (bid < 6152)       { s = xq;  d = dxq;  base = bid; }
  else if (bid < 12304) { s = xkv; d = dxkv; base = bid - 6152; }
  else {
    int r = bid - 12304;
    int wsel = r >> 10; base = r & 1023;
    s = (wsel == 0) ? wq : (wsel == 1) ? wk : (wsel == 2) ? wv : wp;
    d = (wsel == 0) ? dwq : (wsel == 1) ? dwk : (wsel == 2) ? dwv : dwp;
  }
  int i = base * 256 + threadIdx.x;
  float4 f = ((const float4*)s)[i];
  u16x4 o;
  o[0] = f2bf(f.x); o[1] = f2bf(f.y); o[2] = f2bf(f.z); o[3] = f2bf(f.w);
  ((u16x4*)d)[i] = o;
}

// ---------------------------------------------------------------- GEMM mainloop
// (round-5 known-good) 128x128 tile, BK=64, 16 K-iters, XOR-8 chunk-swizzled
// LDS, 0 bank conflicts measured.
__device__ __forceinline__ void gemm_mainloop64(
    const uint16_t* A, const uint16_t* W, int M, int row0, int col0,
    v4f acc[4][4], uint16_t* sA, uint16_t* sB)
{
  const int tid = threadIdx.x;
  const int lane = tid & 63, w = tid >> 6, quad = lane >> 4, l15 = lane & 15;
  const int rbase = (w >> 1) * 64, cbase = (w & 1) * 64;

  const uint16_t* Aptr[4];
  const uint16_t* Bptr[4];
  #pragma unroll
  for (int r = 0; r < 4; r++) {
    int c = r * 256 + tid;
    int row = c >> 3, qp = c & 7;
    int g = qp ^ (row & 7);
    Aptr[r] = A + (size_t)min(row0 + row, M - 1) * 1024 + g * 8;
    Bptr[r] = W + (size_t)(col0 + row) * 1024 + g * 8;
  }

  #pragma unroll
  for (int i = 0; i < 4; i++)
    #pragma unroll
    for (int j = 0; j < 4; j++) acc[i][j] = (v4f)0.0f;

  for (int k0 = 0; k0 < 1024; k0 += 64) {
    #pragma unroll
    for (int r = 0; r < 4; r++) {
      gl_lds16(Aptr[r] + k0, sA + (r * 256 + tid) * 8);
      gl_lds16(Bptr[r] + k0, sB + (r * 256 + tid) * 8);
    }
    __syncthreads();
    #pragma unroll
    for (int s = 0; s < 2; s++) {
      v8s af[4], bf[4];
      #pragma unroll
      for (int i = 0; i < 4; i++) {
        int m = rbase + i * 16 + l15;
        af[i] = *(const v8s*)(sA + m * 64 + (((s * 4 + quad) ^ (m & 7)) * 8));
      }
      #pragma unroll
      for (int j = 0; j < 4; j++) {
        int n = cbase + j * 16 + l15;
        bf[j] = *(const v8s*)(sB + n * 64 + (((s * 4 + quad) ^ (n & 7)) * 8));
      }
      #pragma unroll
      for (int i = 0; i < 4; i++)
        #pragma unroll
        for (int j = 0; j < 4; j++)
          acc[i][j] = __builtin_amdgcn_mfma_f32_16x16x32_bf16(af[i], bf[j], acc[i][j], 0, 0, 0);
    }
    __syncthreads();
  }
}

// Fused QKV projection (Wqkv packed [3072][1024]; ct>>3 selects Q/K/V).
__global__ __launch_bounds__(256) void gemm_qkv(
    const uint16_t* xq, const uint16_t* xkv, const uint16_t* Wqkv,
    const float* bq, const float* bk, const float* bv, const float* freqs,
    uint16_t* Q, uint16_t* K, uint16_t* V)
{
  __shared__ uint16_t sA[128 * 64];
  __shared__ uint16_t sB[128 * 64];
  const int ct = blockIdx.x, rt = blockIdx.y;
  const int z = ct >> 3;
  const int col0 = ct * 128, row0 = rt * 128;
  const uint16_t* A = (z == 0) ? xq : xkv;
  const float* bias  = (z == 0) ? bq : (z == 1 ? bk : bv);
  uint16_t* dst      = (z == 0) ? Q  : (z == 1 ? K  : V);

  v4f acc[4][4];
  gemm_mainloop64(A, Wqkv, NTOK, row0, col0, acc, sA, sB);

  const int tid = threadIdx.x;
  const int lane = tid & 63, w = tid >> 6, quad = lane >> 4, l15 = lane & 15;
  const int rbase = (w >> 1) * 64, cbase = (w & 1) * 64;
  #pragma unroll
  for (int i = 0; i < 4; i++) {
    #pragma unroll
    for (int reg = 0; reg < 4; reg++) {
      int n = row0 + rbase + i * 16 + quad * 4 + reg;
      bool ok = (n < NTOK);
      int nn = min(n, NTOK - 1);
      int b = nn / T_, t = nn % T_;
      float vj[4];
      #pragma unroll
      for (int j = 0; j < 4; j++)
        vj[j] = acc[i][j][reg] + bias[(col0 + cbase + j * 16 + l15) & 1023];
      if (z < 2) {
        float v0 = vj[0], v1 = vj[1];
        float p0 = __shfl_xor(v0, 1);
        float p1 = __shfl_xor(v1, 1);
        float f0 = freqs[t * 32 + l15];
        float f1 = freqs[t * 32 + 16 + l15];
        float s0, c0, s1, c1;
        __sincosf(f0, &s0, &c0);
        __sincosf(f1, &s1, &c1);
        if (l15 & 1) { vj[0] = v0 * c0 + p0 * s0; vj[1] = v1 * c1 + p1 * s1; }
        else         { vj[0] = v0 * c0 - p0 * s0; vj[1] = v1 * c1 - p1 * s1; }
      }
      if (z == 0) {
        #pragma unroll
        for (int j = 0; j < 4; j++) vj[j] *= 0.125f;
      }
      if (ok) {
        #pragma unroll
        for (int j = 0; j < 4; j++) {
          int col = col0 + cbase + j * 16 + l15;
          int h = (col >> 6) & 15, d = col & 63;
          dst[((size_t)(b * H_ + h) * T_ + t) * 64 + d] = f2bf(vj[j]);
        }
      }
    }
  }
}

// Output projection: f32 -> d_out [NTOK][1024]
__global__ __launch_bounds__(256) void gemm_out(
    const uint16_t* Y, const uint16_t* wp, const float* bp, float* out)
{
  __shared__ uint16_t sA[128 * 64];
  __shared__ uint16_t sB[128 * 64];
  const int col0 = blockIdx.x * 128, row0 = blockIdx.y * 128;
  v4f acc[4][4];
  gemm_mainloop64(Y, wp, NTOK, row0, col0, acc, sA, sB);

  const int tid = threadIdx.x;
  const int lane = tid & 63, w = tid >> 6, quad = lane >> 4, l15 = lane & 15;
  const int rbase = (w >> 1) * 64, cbase = (w & 1) * 64;
  #pragma unroll
  for (int i = 0; i < 4; i++) {
    #pragma unroll
    for (int reg = 0; reg < 4; reg++) {
      int n = row0 + rbase + i * 16 + quad * 4 + reg;
      if (n < NTOK) {
        #pragma unroll
        for (int j = 0; j < 4; j++) {
          int col = col0 + cbase + j * 16 + l15;
          out[(size_t)n * 1024 + col] = acc[i][j][reg] + bp[col];
        }
      }
    }
  }
}

// ---------------------------------------------------------------- V transpose
__global__ __launch_bounds__(256) void transpose_v(const uint16_t* Vb, uint16_t* Vt)
{
  __shared__ uint16_t sT[64 * 64];
  const int tid = threadIdx.x;
  const int t0 = blockIdx.x * 64, bh = blockIdx.y;
  const uint16_t* src = Vb + (size_t)bh * T_ * 64;
  #pragma unroll
  for (int r = 0; r < 2; r++) {
    int task = r * 256 + tid;
    int t = task >> 3, oc = task & 7;
    int gt = min(t0 + t, T_ - 1);
    u16x8 v = *(const u16x8*)(src + (size_t)gt * 64 + oc * 8);
    int p = oc ^ (t & 7) ^ ((t >> 3) & 7);
    *(u16x8*)(sT + t * 64 + p * 8) = v;
  }
  __syncthreads();
  uint16_t* dst = Vt + (size_t)bh * 64 * TP_;
  #pragma unroll
  for (int r = 0; r < 2; r++) {
    int task = r * 256 + tid;
    int o = task & 7, d = task >> 3;
    u16x8 v;
    #pragma unroll
    for (int k = 0; k < 8; k++) {
      int t = o * 8 + k;
      int p = (d >> 3) ^ k ^ o;
      v[k] = sT[t * 64 + p * 8 + (d & 7)];
    }
    *(u16x8*)(dst + (size_t)d * TP_ + t0 + o * 8) = v;
  }
}

// ---------------------------------------------------------------- flash attention
// 128 q-rows/block, 4 waves x 32 rows (2 row-frags each, sequential).
// 128-key tiles; fixed-max softmax; sK/sVT gl_lds16-staged XOR-8 swizzled.
// sP per-wave [16][136], reused across the 2 row-frags (wave-private, in-wave
// lgkm ordering handles write->read->overwrite).
__global__ __launch_bounds__(256) void attn(
    const uint16_t* Q, const uint16_t* K, const uint16_t* Vt, uint16_t* Y)
{
  __shared__ uint16_t sK[128 * 64];
  __shared__ uint16_t sVT[64 * 128];
  __shared__ uint16_t sP[4 * 16 * 136];

  const int tid = threadIdx.x;
  const int lane = tid & 63, w = tid >> 6, quad = lane >> 4, l15 = lane & 15;
  const int bh = blockIdx.y, b = bh >> 4, h = bh & 15;
  const int q0 = blockIdx.x * 128;
  const int qw = q0 + w * 32;            // wave's 32-row base

  const uint16_t* Qb = Q + (size_t)bh * T_ * 64;
  const uint16_t* Kb = K + (size_t)bh * T_ * 64;
  const uint16_t* Vtb = Vt + (size_t)bh * 64 * TP_;

  v8s aq[2][2];
  #pragma unroll
  for (int i = 0; i < 2; i++) {
    int qr = min(qw + i * 16 + l15, T_ - 1);
    aq[i][0] = *(const v8s*)(Qb + (size_t)qr * 64 + quad * 8);
    aq[i][1] = *(const v8s*)(Qb + (size_t)qr * 64 + 32 + quad * 8);
  }

  float l_r[2][4];
  v4f o[2][4];
  #pragma unroll
  for (int i = 0; i < 2; i++)
    #pragma unroll
    for (int r = 0; r < 4; r++) { l_r[i][r] = 0.f; o[i][r] = (v4f)0.0f; }

  // allowed: col < COND_ + row; max row in block = q0+127
  const int kend = min(T_, COND_ + q0 + 127);
  const int nkt = (kend + 127) >> 7;

  for (int kt = 0; kt < nkt; kt++) {
    const int k0 = kt * 128;
    #pragma unroll
    for (int r = 0; r < 4; r++) {
      int c = r * 256 + tid;
      int key = c >> 3, qp = c & 7;
      int g = qp ^ (key & 7);
      int gk = min(k0 + key, T_ - 1);
      gl_lds16(Kb + (size_t)gk * 64 + g * 8, sK + c * 8);
    }
    #pragma unroll
    for (int r = 0; r < 4; r++) {
      int c = r * 256 + tid;
      int d = c >> 4, p = c & 15;
      int g = (p & 8) | ((p ^ d) & 7);
      gl_lds16(Vtb + (size_t)d * TP_ + k0 + g * 8, sVT + c * 8);
    }
    __syncthreads();

    uint16_t* pw = sP + w * (16 * 136);
    #pragma unroll
    for (int i = 0; i < 2; i++) {
      // --- S = Q K^T (Q pre-scaled by 1/8)
      v4f s[8];
      #pragma unroll
      for (int cb = 0; cb < 8; cb++) {
        int key_l = cb * 16 + l15;
        v8s b0 = *(const v8s*)(sK + (key_l * 8 + ((quad) ^ (key_l & 7))) * 8);
        v8s b1 = *(const v8s*)(sK + (key_l * 8 + ((4 + quad) ^ (key_l & 7))) * 8);
        v4f zz = (v4f)0.0f;
        zz = __builtin_amdgcn_mfma_f32_16x16x32_bf16(aq[i][0], b0, zz, 0, 0, 0);
        zz = __builtin_amdgcn_mfma_f32_16x16x32_bf16(aq[i][1], b1, zz, 0, 0, 0);
        s[cb] = zz;
      }

      // --- fixed-max softmax: P = exp(S), masked -> 0
      const int rowb = qw + i * 16 + quad * 4;
      const bool full = (k0 + 128 <= COND_ + qw + i * 16) && (k0 + 128 <= T_);
      if (full) {
        #pragma unroll
        for (int reg = 0; reg < 4; reg++) {
          float rs = 0.f;
          #pragma unroll
          for (int cb = 0; cb < 8; cb++) {
            float pv = __expf(s[cb][reg]);
            uint16_t pb = f2bf(pv);
            rs += bf2f(pb);
            pw[(quad * 4 + reg) * 136 + cb * 16 + l15] = pb;
          }
          #pragma unroll
          for (int off = 1; off < 16; off <<= 1) rs += __shfl_xor(rs, off);
          l_r[i][reg] += rs;
        }
      } else {
        #pragma unroll
        for (int reg = 0; reg < 4; reg++) {
          int lim = min(COND_ + rowb + reg, T_);
          float rs = 0.f;
          #pragma unroll
          for (int cb = 0; cb < 8; cb++) {
            int key = k0 + cb * 16 + l15;
            float pv = (key < lim) ? __expf(s[cb][reg]) : 0.f;
            uint16_t pb = f2bf(pv);
            rs += bf2f(pb);
            pw[(quad * 4 + reg) * 136 + cb * 16 + l15] = pb;
          }
          #pragma unroll
          for (int off = 1; off < 16; off <<= 1) rs += __shfl_xor(rs, off);
          l_r[i][reg] += rs;
        }
      }

      // --- O += P V (sP wave-private)
      #pragma unroll
      for (int ks = 0; ks < 4; ks++) {
        v8s ap = *(const v8s*)(pw + l15 * 136 + ks * 32 + quad * 8);
        #pragma unroll
        for (int cbd = 0; cbd < 4; cbd++) {
          int d = cbd * 16 + l15;
          v8s bv = *(const v8s*)(sVT + d * 128 + (((ks * 4 + quad) ^ (d & 7)) * 8));
          o[i][cbd] = __builtin_amdgcn_mfma_f32_16x16x32_bf16(ap, bv, o[i][cbd], 0, 0, 0);
        }
      }
    }
    __syncthreads();
  }

  // --- epilogue: O / l -> Y [B][T][C] bf16
  #pragma unroll
  for (int i = 0; i < 2; i++) {
    #pragma unroll
    for (int reg = 0; reg < 4; reg++) {
      int t = qw + i * 16 + quad * 4 + reg;
      if (t < T_) {
        float inv = 1.0f / l_r[i][reg];
        #pragma unroll
        for (int cbd = 0; cbd < 4; cbd++) {
          int d = cbd * 16 + l15;
          Y[((size_t)(b * T_ + t)) * C_ + h * 64 + d] = f2bf(o[i][cbd][reg] * inv);
        }
      }
    }
  }
}

// ---------------------------------------------------------------- launch
extern "C" void kernel_launch(void* const* d_in, const int* in_sizes, int n_in,
                              void* d_out, int out_size, void* d_ws, size_t ws_size,
                              hipStream_t stream)
{
  const float* x_q   = (const float*)d_in[0];
  const float* x_kv  = (const float*)d_in[1];
  const float* freqs = (const float*)d_in[2];
  const float* Wq = (const float*)d_in[3];
  const float* bq = (const float*)d_in[4];
  const float* Wk = (const float*)d_in[5];
  const float* bk = (const float*)d_in[6];
  const float* Wv = (const float*)d_in[7];
  const float* bv = (const float*)d_in[8];
  const float* Wp = (const float*)d_in[9];
  const float* bp = (const float*)d_in[10];
  float* out = (float*)d_out;

  const size_t SZX = (size_t)NTOK * C_;
  const size_t SZW = (size_t)C_ * C_;
  uint16_t* ws = (uint16_t*)d_ws;
  uint16_t* xq_bf  = ws;
  uint16_t* xkv_bf = xq_bf + SZX;
  uint16_t* wq_bf  = xkv_bf + SZX;   // packed Wqkv[3072][1024]
  uint16_t* wk_bf  = wq_bf + SZW;
  uint16_t* wv_bf  = wk_bf + SZW;
  uint16_t* wp_bf  = wv_bf + SZW;
  uint16_t* Qb = wp_bf + SZW;
  uint16_t* Kb = Qb + SZX;
  uint16_t* Vb = Kb + SZX;
  uint16_t* Vt = ws;                 // alias over dead xq/xkv after qkv
  uint16_t* Yb = Vb;                 // alias over dead natural-V after transpose

  convert_bf16<<<dim3(16400), 256, 0, stream>>>(
      x_q, x_kv, Wq, Wk, Wv, Wp, xq_bf, xkv_bf, wq_bf, wk_bf, wv_bf, wp_bf);

  gemm_qkv<<<dim3(24, 49), 256, 0, stream>>>(
      xq_bf, xkv_bf, wq_bf, bq, bk, bv, freqs, Qb, Kb, Vb);

  transpose_v<<<dim3(13, BH_), 256, 0, stream>>>(Vb, Vt);

  attn<<<dim3(7, BH_), 256, 0, stream>>>(Qb, Kb, Vt, Yb);

  gemm_out<<<dim3(8, 49), 256, 0, stream>>>(Yb, wp_bf, bp, out);
}

// Round 9
// 280.821 us; speedup vs baseline: 1.2321x; 1.0396x over previous
//
#include <hip/hip_runtime.h>
#include <stdint.h>

#define B_    8
#define T_    769
#define C_    1024
#define H_    16
#define COND_ 256
#define NTOK  (B_*T_)     // 6152
#define BH_   (B_*H_)     // 128
#define TP_   896         // padded T for V^T rows (7*128)

typedef short    v8s  __attribute__((ext_vector_type(8)));   // 8 bf16 (4 VGPRs)
typedef float    v4f  __attribute__((ext_vector_type(4)));   // 4 fp32 acc
typedef uint16_t u16x4 __attribute__((ext_vector_type(4)));
typedef uint16_t u16x8 __attribute__((ext_vector_type(8)));
typedef uint32_t u32x4 __attribute__((ext_vector_type(4)));

__device__ __forceinline__ uint16_t f2bf(float f) {
  uint32_t u = __builtin_bit_cast(uint32_t, f);
  u += 0x7fffu + ((u >> 16) & 1u);          // RNE
  return (uint16_t)(u >> 16);
}

__device__ __forceinline__ void gl_lds16(const void* gptr, void* lptr) {
  __builtin_amdgcn_global_load_lds(
      (const __attribute__((address_space(1))) uint32_t*)gptr,
      (__attribute__((address_space(3))) uint32_t*)lptr,
      16, 0, 0);
}

// ---------------------------------------------------------------- convert f32->bf16
__global__ __launch_bounds__(256) void convert_bf16(
    const float* xq, const float* xkv, const float* wq, const float* wk,
    const float* wv, const float* wp,
    uint16_t* dxq, uint16_t* dxkv, uint16_t* dwq, uint16_t* dwk,
    uint16_t* dwv, uint16_t* dwp)
{
  int bid = blockIdx.x;
  const float* s; uint16_t* d; int base;
  if (bid < 6152)       { s = xq;  d = dxq;  base = bid; }
  else if (bid < 12304) { s = xkv; d = dxkv; base = bid - 6152; }
  else {
    int r = bid - 12304;
    int wsel = r >> 10; base = r & 1023;
    s = (wsel == 0) ? wq : (wsel == 1) ? wk : (wsel == 2) ? wv : wp;
    d = (wsel == 0) ? dwq : (wsel == 1) ? dwk : (wsel == 2) ? dwv : dwp;
  }
  int i = base * 256 + threadIdx.x;
  float4 f = ((const float4*)s)[i];
  u16x4 o;
  o[0] = f2bf(f.x); o[1] = f2bf(f.y); o[2] = f2bf(f.z); o[3] = f2bf(f.w);
  ((u16x4*)d)[i] = o;
}

// ---------------------------------------------------------------- GEMM mainloop
// (known-good) 128x128 tile, BK=64, 16 K-iters, XOR-8 chunk-swizzled LDS,
// 0 bank conflicts measured.
__device__ __forceinline__ void gemm_mainloop64(
    const uint16_t* A, const uint16_t* W, int M, int row0, int col0,
    v4f acc[4][4], uint16_t* sA, uint16_t* sB)
{
  const int tid = threadIdx.x;
  const int lane = tid & 63, w = tid >> 6, quad = lane >> 4, l15 = lane & 15;
  const int rbase = (w >> 1) * 64, cbase = (w & 1) * 64;

  const uint16_t* Aptr[4];
  const uint16_t* Bptr[4];
  #pragma unroll
  for (int r = 0; r < 4; r++) {
    int c = r * 256 + tid;
    int row = c >> 3, qp = c & 7;
    int g = qp ^ (row & 7);
    Aptr[r] = A + (size_t)min(row0 + row, M - 1) * 1024 + g * 8;
    Bptr[r] = W + (size_t)(col0 + row) * 1024 + g * 8;
  }

  #pragma unroll
  for (int i = 0; i < 4; i++)
    #pragma unroll
    for (int j = 0; j < 4; j++) acc[i][j] = (v4f)0.0f;

  for (int k0 = 0; k0 < 1024; k0 += 64) {
    #pragma unroll
    for (int r = 0; r < 4; r++) {
      gl_lds16(Aptr[r] + k0, sA + (r * 256 + tid) * 8);
      gl_lds16(Bptr[r] + k0, sB + (r * 256 + tid) * 8);
    }
    __syncthreads();
    #pragma unroll
    for (int s = 0; s < 2; s++) {
      v8s af[4], bf[4];
      #pragma unroll
      for (int i = 0; i < 4; i++) {
        int m = rbase + i * 16 + l15;
        af[i] = *(const v8s*)(sA + m * 64 + (((s * 4 + quad) ^ (m & 7)) * 8));
      }
      #pragma unroll
      for (int j = 0; j < 4; j++) {
        int n = cbase + j * 16 + l15;
        bf[j] = *(const v8s*)(sB + n * 64 + (((s * 4 + quad) ^ (n & 7)) * 8));
      }
      #pragma unroll
      for (int i = 0; i < 4; i++)
        #pragma unroll
        for (int j = 0; j < 4; j++)
          acc[i][j] = __builtin_amdgcn_mfma_f32_16x16x32_bf16(af[i], bf[j], acc[i][j], 0, 0, 0);
    }
    __syncthreads();
  }
}

// Fused QKV projection (Wqkv packed [3072][1024]; ct>>3 selects Q/K/V).
__global__ __launch_bounds__(256) void gemm_qkv(
    const uint16_t* xq, const uint16_t* xkv, const uint16_t* Wqkv,
    const float* bq, const float* bk, const float* bv, const float* freqs,
    uint16_t* Q, uint16_t* K, uint16_t* V)
{
  __shared__ uint16_t sA[128 * 64];
  __shared__ uint16_t sB[128 * 64];
  const int ct = blockIdx.x, rt = blockIdx.y;
  const int z = ct >> 3;
  const int col0 = ct * 128, row0 = rt * 128;
  const uint16_t* A = (z == 0) ? xq : xkv;
  const float* bias  = (z == 0) ? bq : (z == 1 ? bk : bv);
  uint16_t* dst      = (z == 0) ? Q  : (z == 1 ? K  : V);

  v4f acc[4][4];
  gemm_mainloop64(A, Wqkv, NTOK, row0, col0, acc, sA, sB);

  const int tid = threadIdx.x;
  const int lane = tid & 63, w = tid >> 6, quad = lane >> 4, l15 = lane & 15;
  const int rbase = (w >> 1) * 64, cbase = (w & 1) * 64;
  #pragma unroll
  for (int i = 0; i < 4; i++) {
    #pragma unroll
    for (int reg = 0; reg < 4; reg++) {
      int n = row0 + rbase + i * 16 + quad * 4 + reg;
      bool ok = (n < NTOK);
      int nn = min(n, NTOK - 1);
      int b = nn / T_, t = nn % T_;
      float vj[4];
      #pragma unroll
      for (int j = 0; j < 4; j++)
        vj[j] = acc[i][j][reg] + bias[(col0 + cbase + j * 16 + l15) & 1023];
      if (z < 2) {
        float v0 = vj[0], v1 = vj[1];
        float p0 = __shfl_xor(v0, 1);
        float p1 = __shfl_xor(v1, 1);
        float f0 = freqs[t * 32 + l15];
        float f1 = freqs[t * 32 + 16 + l15];
        float s0, c0, s1, c1;
        __sincosf(f0, &s0, &c0);
        __sincosf(f1, &s1, &c1);
        if (l15 & 1) { vj[0] = v0 * c0 + p0 * s0; vj[1] = v1 * c1 + p1 * s1; }
        else         { vj[0] = v0 * c0 - p0 * s0; vj[1] = v1 * c1 - p1 * s1; }
      }
      if (z == 0) {
        #pragma unroll
        for (int j = 0; j < 4; j++) vj[j] *= 0.125f;
      }
      if (ok) {
        #pragma unroll
        for (int j = 0; j < 4; j++) {
          int col = col0 + cbase + j * 16 + l15;
          int h = (col >> 6) & 15, d = col & 63;
          dst[((size_t)(b * H_ + h) * T_ + t) * 64 + d] = f2bf(vj[j]);
        }
      }
    }
  }
}

// Output projection: f32 -> d_out [NTOK][1024]
__global__ __launch_bounds__(256) void gemm_out(
    const uint16_t* Y, const uint16_t* wp, const float* bp, float* out)
{
  __shared__ uint16_t sA[128 * 64];
  __shared__ uint16_t sB[128 * 64];
  const int col0 = blockIdx.x * 128, row0 = blockIdx.y * 128;
  v4f acc[4][4];
  gemm_mainloop64(Y, wp, NTOK, row0, col0, acc, sA, sB);

  const int tid = threadIdx.x;
  const int lane = tid & 63, w = tid >> 6, quad = lane >> 4, l15 = lane & 15;
  const int rbase = (w >> 1) * 64, cbase = (w & 1) * 64;
  #pragma unroll
  for (int i = 0; i < 4; i++) {
    #pragma unroll
    for (int reg = 0; reg < 4; reg++) {
      int n = row0 + rbase + i * 16 + quad * 4 + reg;
      if (n < NTOK) {
        #pragma unroll
        for (int j = 0; j < 4; j++) {
          int col = col0 + cbase + j * 16 + l15;
          out[(size_t)n * 1024 + col] = acc[i][j][reg] + bp[col];
        }
      }
    }
  }
}

// ---------------------------------------------------------------- V transpose (permuted)
// Vb [bh][T][64] -> Vt [bh][64][TP_], where within each 128-key tile, position
// p holds key (p&7)*16 + (p>>3)  (matches attn's permuted P layout).
__global__ __launch_bounds__(256) void transpose_v(const uint16_t* Vb, uint16_t* Vt)
{
  __shared__ uint16_t sT[128 * 64];
  const int tid = threadIdx.x;
  const int t0 = blockIdx.x * 128, bh = blockIdx.y;
  const uint16_t* src = Vb + (size_t)bh * T_ * 64;
  #pragma unroll
  for (int r = 0; r < 4; r++) {
    int task = r * 256 + tid;
    int t = task >> 3, oc = task & 7;
    int gt = min(t0 + t, T_ - 1);
    u16x8 v = *(const u16x8*)(src + (size_t)gt * 64 + oc * 8);
    *(u16x8*)(sT + t * 64 + ((oc ^ (t & 7)) * 8)) = v;
  }
  __syncthreads();
  uint16_t* dst = Vt + (size_t)bh * 64 * TP_;
  #pragma unroll
  for (int r = 0; r < 4; r++) {
    int d = tid & 63, c = (tid >> 6) + r * 4;   // c = position-chunk 0..15
    u16x8 v;
    #pragma unroll
    for (int j = 0; j < 8; j++) {
      int t = j * 16 + c;                       // key for position c*8+j
      v[j] = sT[t * 64 + (((d >> 3) ^ (t & 7)) * 8) + (d & 7)];
    }
    *(u16x8*)(dst + (size_t)d * TP_ + t0 + c * 8) = v;
  }
}

// ---------------------------------------------------------------- flash attention
// 4 waves x 16 q-rows = 64 q-rows/block; 128-key tiles; fixed-max softmax.
// P stored column-permuted (pos p <-> key (p&7)*16+(p>>3)): each lane's 8 exp
// values are contiguous -> pack + single ds_write_b128 per reg. Row l (sum
// of P) accumulated by an extra MFMA against a ones-vector (reuses ap).
// sP stride 136 (68 words = 4 mod 32) -> uniform bank use, no swizzle needed.
__global__ __launch_bounds__(256) void attn(
    const uint16_t* Q, const uint16_t* K, const uint16_t* Vt, uint16_t* Y)
{
  __shared__ uint16_t sK[128 * 64];
  __shared__ uint16_t sVT[64 * 128];
  __shared__ uint16_t sP[4 * 16 * 136];

  const int tid = threadIdx.x;
  const int lane = tid & 63, w = tid >> 6, quad = lane >> 4, l15 = lane & 15;
  const int bh = blockIdx.y, b = bh >> 4, h = bh & 15;
  const int q0 = blockIdx.x * 64;

  const uint16_t* Qb = Q + (size_t)bh * T_ * 64;
  const uint16_t* Kb = K + (size_t)bh * T_ * 64;
  const uint16_t* Vtb = Vt + (size_t)bh * 64 * TP_;

  const int qr = min(q0 + w * 16 + l15, T_ - 1);
  v8s aq0 = *(const v8s*)(Qb + (size_t)qr * 64 + quad * 8);
  v8s aq1 = *(const v8s*)(Qb + (size_t)qr * 64 + 32 + quad * 8);

  v8s vones;
  #pragma unroll
  for (int j = 0; j < 8; j++) vones[j] = (short)0x3F80;   // bf16 1.0

  v4f lacc = (v4f)0.0f;
  v4f o[4];
  #pragma unroll
  for (int r = 0; r < 4; r++) o[r] = (v4f)0.0f;

  const int kend = min(T_, q0 + 319);       // max col = 255 + (q0+63)
  const int nkt = (kend + 127) >> 7;

  for (int kt = 0; kt < nkt; kt++) {
    const int k0 = kt * 128;
    // --- stage K tile (natural layout, XOR-8 swizzle)
    #pragma unroll
    for (int r = 0; r < 4; r++) {
      int c = r * 256 + tid;
      int key = c >> 3, qp = c & 7;
      int g = qp ^ (key & 7);
      int gk = min(k0 + key, T_ - 1);
      gl_lds16(Kb + (size_t)gk * 64 + g * 8, sK + c * 8);
    }
    // --- stage V^T tile (pre-permuted global, XOR swizzle on 16 chunks/row)
    #pragma unroll
    for (int r = 0; r < 4; r++) {
      int c = r * 256 + tid;
      int d = c >> 4, p = c & 15;
      int g = (p & 8) | ((p ^ d) & 7);
      gl_lds16(Vtb + (size_t)d * TP_ + k0 + g * 8, sVT + c * 8);
    }
    __syncthreads();

    // --- S = Q K^T (Q pre-scaled by 1/8): 8 key frags x 2 k-steps
    v4f s[8];
    #pragma unroll
    for (int cb = 0; cb < 8; cb++) {
      int key_l = cb * 16 + l15;
      v8s b0 = *(const v8s*)(sK + (key_l * 8 + ((quad) ^ (key_l & 7))) * 8);
      v8s b1 = *(const v8s*)(sK + (key_l * 8 + ((4 + quad) ^ (key_l & 7))) * 8);
      v4f zz = (v4f)0.0f;
      zz = __builtin_amdgcn_mfma_f32_16x16x32_bf16(aq0, b0, zz, 0, 0, 0);
      zz = __builtin_amdgcn_mfma_f32_16x16x32_bf16(aq1, b1, zz, 0, 0, 0);
      s[cb] = zz;
    }

    // --- fixed-max softmax: P = exp(S) (masked -> 0), permuted b128 store
    uint16_t* pw = sP + w * (16 * 136);
    const bool full = (k0 + 128 <= COND_ + q0) && (k0 + 128 <= T_);
    #pragma unroll
    for (int reg = 0; reg < 4; reg++) {
      const int lr = quad * 4 + reg;
      float pv[8];
      if (full) {
        #pragma unroll
        for (int cb = 0; cb < 8; cb++) pv[cb] = __expf(s[cb][reg]);
      } else {
        int lim = min(COND_ + q0 + w * 16 + lr, T_);
        #pragma unroll
        for (int cb = 0; cb < 8; cb++) {
          int key = k0 + cb * 16 + l15;
          pv[cb] = (key < lim) ? __expf(s[cb][reg]) : 0.f;
        }
      }
      u32x4 pk;
      #pragma unroll
      for (int cc = 0; cc < 4; cc++)
        pk[cc] = (uint32_t)f2bf(pv[2 * cc]) | ((uint32_t)f2bf(pv[2 * cc + 1]) << 16);
      *(u32x4*)(pw + lr * 136 + l15 * 8) = pk;
    }

    // --- O += P V ; l += P 1  (sP wave-private; in-wave lgkm ordering)
    #pragma unroll
    for (int ks = 0; ks < 4; ks++) {
      v8s ap = *(const v8s*)(pw + l15 * 136 + (ks * 4 + quad) * 8);
      lacc = __builtin_amdgcn_mfma_f32_16x16x32_bf16(ap, vones, lacc, 0, 0, 0);
      #pragma unroll
      for (int cbd = 0; cbd < 4; cbd++) {
        int d = cbd * 16 + l15;
        v8s bv = *(const v8s*)(sVT + d * 128 + (((ks * 4 + quad) ^ (d & 7)) * 8));
        o[cbd] = __builtin_amdgcn_mfma_f32_16x16x32_bf16(ap, bv, o[cbd], 0, 0, 0);
      }
    }
    __syncthreads();   // safe to restage K/V next iter
  }

  // --- epilogue: O / l -> Y [B][T][C] bf16
  #pragma unroll
  for (int reg = 0; reg < 4; reg++) {
    int t = q0 + w * 16 + quad * 4 + reg;
    if (t < T_) {
      float inv = 1.0f / lacc[reg];
      #pragma unroll
      for (int cbd = 0; cbd < 4; cbd++) {
        int d = cbd * 16 + l15;
        Y[((size_t)(b * T_ + t)) * C_ + h * 64 + d] = f2bf(o[cbd][reg] * inv);
      }
    }
  }
}

// ---------------------------------------------------------------- launch
extern "C" void kernel_launch(void* const* d_in, const int* in_sizes, int n_in,
                              void* d_out, int out_size, void* d_ws, size_t ws_size,
                              hipStream_t stream)
{
  const float* x_q   = (const float*)d_in[0];
  const float* x_kv  = (const float*)d_in[1];
  const float* freqs = (const float*)d_in[2];
  const float* Wq = (const float*)d_in[3];
  const float* bq = (const float*)d_in[4];
  const float* Wk = (const float*)d_in[5];
  const float* bk = (const float*)d_in[6];
  const float* Wv = (const float*)d_in[7];
  const float* bv = (const float*)d_in[8];
  const float* Wp = (const float*)d_in[9];
  const float* bp = (const float*)d_in[10];
  float* out = (float*)d_out;

  const size_t SZX = (size_t)NTOK * C_;
  const size_t SZW = (size_t)C_ * C_;
  uint16_t* ws = (uint16_t*)d_ws;
  uint16_t* xq_bf  = ws;
  uint16_t* xkv_bf = xq_bf + SZX;
  uint16_t* wq_bf  = xkv_bf + SZX;   // packed Wqkv[3072][1024]
  uint16_t* wk_bf  = wq_bf + SZW;
  uint16_t* wv_bf  = wk_bf + SZW;
  uint16_t* wp_bf  = wv_bf + SZW;
  uint16_t* Qb = wp_bf + SZW;
  uint16_t* Kb = Qb + SZX;
  uint16_t* Vb = Kb + SZX;
  uint16_t* Vt = ws;                 // alias over dead xq/xkv after qkv
  uint16_t* Yb = Vb;                 // alias over dead natural-V after transpose

  convert_bf16<<<dim3(16400), 256, 0, stream>>>(
      x_q, x_kv, Wq, Wk, Wv, Wp, xq_bf, xkv_bf, wq_bf, wk_bf, wv_bf, wp_bf);

  gemm_qkv<<<dim3(24, 49), 256, 0, stream>>>(
      xq_bf, xkv_bf, wq_bf, bq, bk, bv, freqs, Qb, Kb, Vb);

  transpose_v<<<dim3(7, BH_), 256, 0, stream>>>(Vb, Vt);

  attn<<<dim3(13, BH_), 256, 0, stream>>>(Qb, Kb, Vt, Yb);

  gemm_out<<<dim3(8, 49), 256, 0, stream>>>(Yb, wp_bf, bp, out);
}